// Round 9
// baseline (52.820 us; speedup 1.0000x reference)
//
#include <hip/hip_runtime.h>
#include <hip/hip_bf16.h>

// Problem constants: B=32, T=256, N=1024 -> R = 8192 rows, K = N-1 = 1023 (padded to 1024)
// alpha = 0.5, b[m] = sqrt(m+1)-sqrt(m) = 1/(sqrt(m+1)+sqrt(m)), coef = sqrt(1023)/Gamma(1.5)
#define COEF 36.090511f
#define INV_COUNT (1.0f / 8388608.0f)   // 1 / (32*256*1024)

typedef __attribute__((ext_vector_type(4))) float f32x4;
typedef __attribute__((ext_vector_type(2))) unsigned long long u64x2;

typedef const __attribute__((address_space(1))) unsigned int* gas_ptr;
typedef __attribute__((address_space(3))) unsigned int* las_ptr;

__device__ __forceinline__ void load_lds16(const void* g, void* l) {
  __builtin_amdgcn_global_load_lds((gas_ptr)g, (las_ptr)l, 16, 0, 0);
}

// manual OCP e4m3fn decode (bias 7): exact
__device__ __forceinline__ float fp8_dec(unsigned int v) {
  const unsigned e = (v >> 3) & 0xF, m = v & 7;
  const int mant = e ? (8 + (int)m) : (int)m;
  const int ee = e ? (int)e : 1;
  float f = (float)mant * __int_as_float((ee + 117) << 23);  // mant * 2^(ee-10)
  return (v & 0x80) ? -f : f;
}

// prep blocks 0..8191: du8 = fp8(u_pred diffs), col 1023 = 0 pad; per-row partials.
// blocks 8192..9215: Mt8[i][j] = fp8(b[i-j]); block 9215 also zeroes the done-counter.
__global__ void prep(const float* __restrict__ up, const float* __restrict__ utr,
                     unsigned char* __restrict__ du8, unsigned char* __restrict__ Mt8,
                     float* __restrict__ dpart, float* __restrict__ ppart,
                     int* __restrict__ counter) {
  const int t = threadIdx.x;      // 256 threads
  if (blockIdx.x >= 8192) {
    const int i = blockIdx.x - 8192;    // Mt row 0..1023
    if (i == 1023 && t == 0) *counter = 0;   // reset done-counter every call (graph-replay safe)
    const int j0 = t * 4;
    float v[4];
#pragma unroll
    for (int e = 0; e < 4; e++) {
      int m = i - (j0 + e);
      v[e] = 0.f;
      if (m >= 0) { float fm_ = (float)m; v[e] = 1.0f / (sqrtf(fm_ + 1.f) + sqrtf(fm_)); }
    }
    int w_ = __builtin_amdgcn_cvt_pk_fp8_f32(v[0], v[1], 0, false);
    w_ = __builtin_amdgcn_cvt_pk_fp8_f32(v[2], v[3], w_, true);
    *(unsigned int*)(Mt8 + (size_t)i * 1024 + j0) = (unsigned int)w_;
    return;
  }

  const int r = blockIdx.x;       // 8192 rows
  const int j0 = t * 4;
  const float* rowp = up + (size_t)r * 1024;

  f32x4 a = *(const f32x4*)(rowp + j0);
  float a4 = (t < 255) ? rowp[j0 + 4] : 0.f;
  f32x4 b = *(const f32x4*)(utr + (size_t)r * 1024 + j0);

  float d0 = a[1] - a[0];
  float d1 = a[2] - a[1];
  float d2 = a[3] - a[2];
  float d3 = (t < 255) ? (a4 - a[3]) : 0.f;   // du[1023] = 0 pad

  int w_ = __builtin_amdgcn_cvt_pk_fp8_f32(d0, d1, 0, false);
  w_ = __builtin_amdgcn_cvt_pk_fp8_f32(d2, d3, w_, true);
  *(unsigned int*)(du8 + (size_t)r * 1024 + j0) = (unsigned int)w_;

  float e0 = a[0] - b[0], e1 = a[1] - b[1], e2 = a[2] - b[2], e3 = a[3] - b[3];
  float dsum = e0 * e0 + e1 * e1 + e2 * e2 + e3 * e3;

#pragma unroll
  for (int off = 32; off > 0; off >>= 1) dsum += __shfl_down(dsum, off, 64);
  __shared__ float ws4[4];
  const int lane = t & 63, w = t >> 6;
  if (lane == 0) ws4[w] = dsum;
  __syncthreads();
  if (t == 0) {
    dpart[r] = ws4[0] + ws4[1] + ws4[2] + ws4[3];
    ppart[r] = d0 * d0;   // physics residual at n=0: u_t = du[r,0], frac_lap[0] = 0
  }
}

// Y[r,i] = sum_j du[r,j] * b[i-j]; fused epilogue: resid = u_t - COEF*Y, accumulate resid^2.
// fp8 GEMM: 128x128 tile, BK=128 bytes, 4 waves, double-buffered LDS, XOR quad-swizzle,
// counted vmcnt(8), XCD+triangular-robust map. Finalize folded in: last block (device
// atomic done-counter) reduces all partials and writes the 3 outputs — no 3rd kernel.
__launch_bounds__(256, 2)
__global__ void gemm(const unsigned char* __restrict__ du8,
                     const unsigned char* __restrict__ Mt8,
                     float* __restrict__ gpart,
                     const float* __restrict__ dpart, const float* __restrict__ ppart,
                     int* __restrict__ counter, float* __restrict__ out) {
  __shared__ unsigned char sA[2][16384];   // [128 rows][128 k-bytes], quad-swizzled
  __shared__ unsigned char sB[2][16384];
  __shared__ float wsum[4];
  __shared__ float sd4[4], sp4[4];
  __shared__ int amLast;

  const int t = threadIdx.x;
  const int w = t >> 6;
  const int lane = t & 63;

  const int bid = blockIdx.x;      // 0..511
  const int xcd = bid & 7;
  const int local = bid >> 3;      // 0..63
  const int e = local & 1;
  const int j = local >> 1;        // 0..31
  const int h = (j < 16) ? (j & 7) : 7 - (j & 7);
  const int cb = e ? 7 - h : h;                 // pairs (2k,2k+1) and (k,k+32) both sum to 7
  const int rb = xcd * 8 + (((j >> 3) << 1) | e);   // bijective with cb per XCD
  const int row0 = rb * 128;
  const int col0 = cb * 128;
  const int nkb = cb + 1;          // K-blocks of 128 bytes (triangular skip)

  const f32x4 vzero = {0.f, 0.f, 0.f, 0.f};
  f32x4 acc[4][4];
#pragma unroll
  for (int i = 0; i < 4; i++)
#pragma unroll
    for (int jj = 0; jj < 4; jj++) acc[i][jj] = vzero;

  // staging: thread t covers (row = t>>3, phys quad = t&7); source quad = phys ^ (row&7)
  const int srow = t >> 3;                            // 0..31
  const int scol = ((t & 7) ^ (srow & 7)) * 16;       // pre-swizzled source byte col
  const unsigned char* gA0 = du8 + (size_t)(row0 + srow) * 1024 + scol;
  const unsigned char* gB0 = Mt8 + (size_t)(col0 + srow) * 1024 + scol;

  auto stage = [&](int buf, int kb) {
    const int kc = kb * 128;
#pragma unroll
    for (int l = 0; l < 4; l++)
      load_lds16(gA0 + (size_t)l * 32 * 1024 + kc, (void*)&sA[buf][l * 4096 + t * 16]);
#pragma unroll
    for (int l = 0; l < 4; l++)
      load_lds16(gB0 + (size_t)l * 32 * 1024 + kc, (void*)&sB[buf][l * 4096 + t * 16]);
  };

  const int wm = w >> 1, wn = w & 1;
  const int frow = lane & 15;
  const int g4 = lane >> 4;              // lane's k-owner group 0..3

  auto compute = [&](int buf) {
#pragma unroll
    for (int p = 0; p < 2; p++) {
      const int lq = g4 * 2 + p;               // logical quad
      const int ph = lq ^ (frow & 7);          // physical quad (swizzle)
      u64x2 aV[4], bV[4];
#pragma unroll
      for (int fm = 0; fm < 4; fm++)
        aV[fm] = *(const u64x2*)&sA[buf][(wm * 64 + fm * 16 + frow) * 128 + ph * 16];
#pragma unroll
      for (int fn = 0; fn < 4; fn++)
        bV[fn] = *(const u64x2*)&sB[buf][(wn * 64 + fn * 16 + frow) * 128 + ph * 16];
#pragma unroll
      for (int fm = 0; fm < 4; fm++)
#pragma unroll
        for (int fn = 0; fn < 4; fn++) {
          acc[fm][fn] = __builtin_amdgcn_mfma_f32_16x16x32_fp8_fp8(
              (long long)aV[fm].x, (long long)bV[fn].x, acc[fm][fn], 0, 0, 0);
          acc[fm][fn] = __builtin_amdgcn_mfma_f32_16x16x32_fp8_fp8(
              (long long)aV[fm].y, (long long)bV[fn].y, acc[fm][fn], 0, 0, 0);
        }
    }
  };

  stage(0, 0);
  for (int kb = 0; kb < nkb; kb++) {
    // BARRIER A: all waves done computing kb-1 -> buf (kb+1)&1 free to overwrite
    asm volatile("" ::: "memory");
    __builtin_amdgcn_s_barrier();
    asm volatile("" ::: "memory");
    if (kb + 1 < nkb) {
      stage((kb + 1) & 1, kb + 1);                    // 8 loads in flight across barrier
      asm volatile("s_waitcnt vmcnt(8)" ::: "memory"); // current tile's 8 complete
    } else {
      asm volatile("s_waitcnt vmcnt(0)" ::: "memory"); // last tile: drain
    }
    // BARRIER B: every wave's current-tile loads complete
    __builtin_amdgcn_s_barrier();
    asm volatile("" ::: "memory");
    compute(kb & 1);
  }

  // fused epilogue: C/D layout col = lane&15, row = (lane>>4)*4 + reg  [HW-verified]
  float psum = 0.f;
  const int rbase = row0 + wm * 64 + (lane >> 4) * 4;
  const int ibase = col0 + wn * 64 + frow;
#pragma unroll
  for (int fm = 0; fm < 4; fm++) {
#pragma unroll
    for (int fn = 0; fn < 4; fn++) {
      const int icol = ibase + fn * 16;        // du index i; output position n = i+1
      if (icol < 1023) {
#pragma unroll
        for (int reg = 0; reg < 4; reg++) {
          const int r = rbase + fm * 16 + reg;
          float frac = COEF * acc[fm][fn][reg];
          float dui = fp8_dec(du8[(size_t)r * 1024 + icol]);
          float ut;
          if (icol == 1022) {
            ut = dui;                           // n = N-1 edge: u_t = du[N-2]
          } else {
            float dui1 = fp8_dec(du8[(size_t)r * 1024 + icol + 1]);
            ut = 0.5f * (dui + dui1);           // central difference
          }
          float res = ut - frac;
          psum += res * res;
        }
      }
    }
  }

#pragma unroll
  for (int off = 32; off > 0; off >>= 1) psum += __shfl_down(psum, off, 64);
  if (lane == 0) wsum[w] = psum;
  __syncthreads();

  // publish this block's partial, then last-done block reduces everything (no 3rd kernel)
  if (t == 0) {
    gpart[bid] = wsum[0] + wsum[1] + wsum[2] + wsum[3];
    __threadfence();                          // release: gpart visible device-wide
    int old = atomicAdd(counter, 1);          // device-scope RMW
    amLast = (old == 511);
  }
  __syncthreads();
  if (!amLast) return;

  __threadfence();                            // acquire: see all blocks' gpart
  float ds = 0.f, ps = 0.f;
  for (int i = t; i < 8192; i += 256) { ds += dpart[i]; ps += ppart[i]; }
  for (int i = t; i < 512; i += 256) ps += gpart[i];
#pragma unroll
  for (int off = 32; off > 0; off >>= 1) {
    ds += __shfl_down(ds, off, 64);
    ps += __shfl_down(ps, off, 64);
  }
  if (lane == 0) { sd4[w] = ds; sp4[w] = ps; }
  __syncthreads();
  if (t == 0) {
    float data = (sd4[0] + sd4[1] + sd4[2] + sd4[3]) * INV_COUNT;
    float phys = (sp4[0] + sp4[1] + sp4[2] + sp4[3]) * INV_COUNT;
    out[0] = data + 0.1f * phys;
    out[1] = data;
    out[2] = phys;
  }
}

extern "C" void kernel_launch(void* const* d_in, const int* in_sizes, int n_in,
                              void* d_out, int out_size, void* d_ws, size_t ws_size,
                              hipStream_t stream) {
  const float* u_pred = (const float*)d_in[0];
  const float* u_true = (const float*)d_in[1];
  float* out = (float*)d_out;

  char* ws = (char*)d_ws;
  float* dpart = (float*)ws;                                    // 8192 floats (32 KiB)
  float* ppart = (float*)(ws + 32768);                          // 8192 floats (32 KiB)
  float* gpart = (float*)(ws + 65536);                          // 512 floats (2 KiB)
  int* counter = (int*)(ws + 67584);                            // 1 int (zeroed by prep)
  unsigned char* Mt8 = (unsigned char*)(ws + 131072);           // 1024*1024 = 1 MiB
  unsigned char* du8 = (unsigned char*)(ws + 131072 + 1048576); // 8192*1024 = 8 MiB

  prep<<<9216, 256, 0, stream>>>(u_pred, u_true, du8, Mt8, dpart, ppart, counter);
  gemm<<<512, 256, 0, stream>>>(du8, Mt8, gpart, dpart, ppart, counter, out);
}

// Round 11
// 39.285 us; speedup vs baseline: 1.3445x; 1.3445x over previous
//
#include <hip/hip_runtime.h>
#include <hip/hip_bf16.h>

// Problem constants: B=32, T=256, N=1024 -> R = 8192 rows, K = N-1 = 1023 (padded to 1024)
// alpha = 0.5, b[m] = sqrt(m+1)-sqrt(m) = 1/(sqrt(m+1)+sqrt(m)), coef = sqrt(1023)/Gamma(1.5)
#define COEF 36.090511f
#define INV_COUNT (1.0f / 8388608.0f)   // 1 / (32*256*1024)

typedef __attribute__((ext_vector_type(4))) float f32x4;
typedef __attribute__((ext_vector_type(2))) unsigned long long u64x2;

typedef const __attribute__((address_space(1))) unsigned int* gas_ptr;
typedef __attribute__((address_space(3))) unsigned int* las_ptr;

__device__ __forceinline__ void load_lds16(const void* g, void* l) {
  __builtin_amdgcn_global_load_lds((gas_ptr)g, (las_ptr)l, 16, 0, 0);
}

// manual OCP e4m3fn decode (bias 7): exact
__device__ __forceinline__ float fp8_dec(unsigned int v) {
  const unsigned e = (v >> 3) & 0xF, m = v & 7;
  const int mant = e ? (8 + (int)m) : (int)m;
  const int ee = e ? (int)e : 1;
  float f = (float)mant * __int_as_float((ee + 117) << 23);  // mant * 2^(ee-10)
  return (v & 0x80) ? -f : f;
}

// prep blocks 0..8191: du8 = fp8(u_pred diffs), col 1023 = 0 pad; per-row partials.
// blocks 8192..9215: Mt8[i][j] = fp8(b[i-j]) (transposed PURE Toeplitz; u_t stays in epilogue
// at f32 precision — folding it into fp8 coefficients failed accuracy in R10).
__global__ void prep(const float* __restrict__ up, const float* __restrict__ utr,
                     unsigned char* __restrict__ du8, unsigned char* __restrict__ Mt8,
                     float* __restrict__ dpart, float* __restrict__ ppart) {
  const int t = threadIdx.x;      // 256 threads
  if (blockIdx.x >= 8192) {
    const int i = blockIdx.x - 8192;    // Mt row 0..1023
    const int j0 = t * 4;
    float v[4];
#pragma unroll
    for (int e = 0; e < 4; e++) {
      int m = i - (j0 + e);
      v[e] = 0.f;
      if (m >= 0) { float fm_ = (float)m; v[e] = 1.0f / (sqrtf(fm_ + 1.f) + sqrtf(fm_)); }
    }
    int w_ = __builtin_amdgcn_cvt_pk_fp8_f32(v[0], v[1], 0, false);
    w_ = __builtin_amdgcn_cvt_pk_fp8_f32(v[2], v[3], w_, true);
    *(unsigned int*)(Mt8 + (size_t)i * 1024 + j0) = (unsigned int)w_;
    return;
  }

  const int r = blockIdx.x;       // 8192 rows
  const int j0 = t * 4;
  const float* rowp = up + (size_t)r * 1024;

  f32x4 a = *(const f32x4*)(rowp + j0);
  f32x4 b = *(const f32x4*)(utr + (size_t)r * 1024 + j0);

  // a4 = a[0] of lane+1 (next 4-chunk's first elem); wave-edge lanes load scalar
  float a4 = __shfl_down(a[0], 1, 64);
  if ((t & 63) == 63 && t < 255) a4 = rowp[j0 + 4];

  float d0 = a[1] - a[0];
  float d1 = a[2] - a[1];
  float d2 = a[3] - a[2];
  float d3 = (t < 255) ? (a4 - a[3]) : 0.f;   // du[1023] = 0 pad

  int w_ = __builtin_amdgcn_cvt_pk_fp8_f32(d0, d1, 0, false);
  w_ = __builtin_amdgcn_cvt_pk_fp8_f32(d2, d3, w_, true);
  *(unsigned int*)(du8 + (size_t)r * 1024 + j0) = (unsigned int)w_;

  float e0 = a[0] - b[0], e1 = a[1] - b[1], e2 = a[2] - b[2], e3 = a[3] - b[3];
  float dsum = e0 * e0 + e1 * e1 + e2 * e2 + e3 * e3;

#pragma unroll
  for (int off = 32; off > 0; off >>= 1) dsum += __shfl_down(dsum, off, 64);
  __shared__ float ws4[4];
  const int lane = t & 63, w = t >> 6;
  if (lane == 0) ws4[w] = dsum;
  __syncthreads();
  if (t == 0) {
    dpart[r] = ws4[0] + ws4[1] + ws4[2] + ws4[3];
    ppart[r] = d0 * d0;   // physics residual at n=0: u_t = du[r,0], frac_lap[0] = 0
  }
}

// Y[r,i] = sum_j du[r,j] * b[i-j]; fused epilogue: resid = u_t - COEF*Y, psum += resid^2.
// fp8 GEMM: 128x128 tile, BK=128 bytes, 4 waves, double-buffered LDS, XOR quad-swizzle,
// counted vmcnt(8), XCD+triangular-robust map. Epilogue reads du from the LAST A-tile in
// LDS (it covers exactly cols [col0,col0+128)) — no scattered global byte loads.
// Block also pre-reduces its 16-row slice of dpart/ppart -> finalize reads 1K floats.
__launch_bounds__(256, 2)
__global__ void gemm(const unsigned char* __restrict__ du8,
                     const unsigned char* __restrict__ Mt8,
                     float* __restrict__ gpart,
                     const float* __restrict__ dpart, const float* __restrict__ ppart) {
  __shared__ unsigned char sA[2][16384];   // [128 rows][128 k-bytes], quad-swizzled
  __shared__ unsigned char sB[2][16384];
  __shared__ float wsum[4];

  const int t = threadIdx.x;
  const int w = t >> 6;
  const int lane = t & 63;

  const int bid = blockIdx.x;      // 0..511
  const int xcd = bid & 7;
  const int local = bid >> 3;      // 0..63
  const int e = local & 1;
  const int j = local >> 1;        // 0..31
  const int h = (j < 16) ? (j & 7) : 7 - (j & 7);
  const int cb = e ? 7 - h : h;                 // pairs (2k,2k+1) and (k,k+32) both sum to 7
  const int rb = xcd * 8 + (((j >> 3) << 1) | e);   // bijective with cb per XCD
  const int row0 = rb * 128;
  const int col0 = cb * 128;
  const int nkb = cb + 1;          // K-blocks of 128 bytes (triangular skip)

  const f32x4 vzero = {0.f, 0.f, 0.f, 0.f};
  f32x4 acc[4][4];
#pragma unroll
  for (int i = 0; i < 4; i++)
#pragma unroll
    for (int jj = 0; jj < 4; jj++) acc[i][jj] = vzero;

  // staging: thread t covers (row = t>>3, phys quad = t&7); source quad = phys ^ (row&7)
  const int srow = t >> 3;                            // 0..31
  const int scol = ((t & 7) ^ (srow & 7)) * 16;       // pre-swizzled source byte col
  const unsigned char* gA0 = du8 + (size_t)(row0 + srow) * 1024 + scol;
  const unsigned char* gB0 = Mt8 + (size_t)(col0 + srow) * 1024 + scol;

  auto stage = [&](int buf, int kb) {
    const int kc = kb * 128;
#pragma unroll
    for (int l = 0; l < 4; l++)
      load_lds16(gA0 + (size_t)l * 32 * 1024 + kc, (void*)&sA[buf][l * 4096 + t * 16]);
#pragma unroll
    for (int l = 0; l < 4; l++)
      load_lds16(gB0 + (size_t)l * 32 * 1024 + kc, (void*)&sB[buf][l * 4096 + t * 16]);
  };

  const int wm = w >> 1, wn = w & 1;
  const int frow = lane & 15;
  const int g4 = lane >> 4;              // lane's k-owner group 0..3

  auto compute = [&](int buf) {
#pragma unroll
    for (int p = 0; p < 2; p++) {
      const int lq = g4 * 2 + p;               // logical quad
      const int ph = lq ^ (frow & 7);          // physical quad (swizzle)
      u64x2 aV[4], bV[4];
#pragma unroll
      for (int fm = 0; fm < 4; fm++)
        aV[fm] = *(const u64x2*)&sA[buf][(wm * 64 + fm * 16 + frow) * 128 + ph * 16];
#pragma unroll
      for (int fn = 0; fn < 4; fn++)
        bV[fn] = *(const u64x2*)&sB[buf][(wn * 64 + fn * 16 + frow) * 128 + ph * 16];
#pragma unroll
      for (int fm = 0; fm < 4; fm++)
#pragma unroll
        for (int fn = 0; fn < 4; fn++) {
          acc[fm][fn] = __builtin_amdgcn_mfma_f32_16x16x32_fp8_fp8(
              (long long)aV[fm].x, (long long)bV[fn].x, acc[fm][fn], 0, 0, 0);
          acc[fm][fn] = __builtin_amdgcn_mfma_f32_16x16x32_fp8_fp8(
              (long long)aV[fm].y, (long long)bV[fn].y, acc[fm][fn], 0, 0, 0);
        }
    }
  };

  stage(0, 0);
  for (int kb = 0; kb < nkb; kb++) {
    // BARRIER A: all waves done computing kb-1 -> buf (kb+1)&1 free to overwrite
    asm volatile("" ::: "memory");
    __builtin_amdgcn_s_barrier();
    asm volatile("" ::: "memory");
    if (kb + 1 < nkb) {
      stage((kb + 1) & 1, kb + 1);                    // 8 loads in flight across barrier
      asm volatile("s_waitcnt vmcnt(8)" ::: "memory"); // current tile's 8 complete
    } else {
      asm volatile("s_waitcnt vmcnt(0)" ::: "memory"); // last tile: drain
    }
    // BARRIER B: every wave's current-tile loads complete
    __builtin_amdgcn_s_barrier();
    asm volatile("" ::: "memory");
    compute(kb & 1);
  }

  // fused epilogue: C/D layout col = lane&15, row = (lane>>4)*4 + reg  [HW-verified].
  // du bytes come from the LAST A-tile in LDS: sA[lastBuf] holds rows [row0,row0+128),
  // k-bytes [col0,col0+128) with byte (rt, c) at rt*128 + ((c>>4)^(rt&7))*16 + (c&15).
  const int lastBuf = (nkb - 1) & 1;
  float psum = 0.f;
#pragma unroll
  for (int fm = 0; fm < 4; fm++) {
#pragma unroll
    for (int fn = 0; fn < 4; fn++) {
      const int c = wn * 64 + fn * 16 + frow;    // col within tile
      const int icol = col0 + c;                 // du index i; output position n = i+1
      if (icol < 1023) {
#pragma unroll
        for (int reg = 0; reg < 4; reg++) {
          const int rt = wm * 64 + g4 * 4 + fm * 16 + reg;   // row within tile
          float frac = COEF * acc[fm][fn][reg];
          float dui = fp8_dec(sA[lastBuf][rt * 128 + (((c >> 4) ^ (rt & 7)) << 4) + (c & 15)]);
          float ut;
          if (icol == 1022) {
            ut = dui;                            // n = N-1 edge: u_t = du[N-2]
          } else {
            float dui1;
            if (c == 127) {                      // tile edge: one global byte (cb<7 only here)
              dui1 = fp8_dec(du8[(size_t)(row0 + rt) * 1024 + icol + 1]);
            } else {
              const int c1 = c + 1;
              dui1 = fp8_dec(sA[lastBuf][rt * 128 + (((c1 >> 4) ^ (rt & 7)) << 4) + (c1 & 15)]);
            }
            ut = 0.5f * (dui + dui1);            // central difference
          }
          float res = ut - frac;
          psum += res * res;
        }
      }
    }
  }

#pragma unroll
  for (int off = 32; off > 0; off >>= 1) psum += __shfl_down(psum, off, 64);
  if (lane == 0) wsum[w] = psum;

  // pre-reduce this block's 16-row slice of dpart/ppart (wave 0, one cache line each)
  float ds_ = 0.f, ps_ = 0.f;
  if (w == 0) {
    if (t < 16) { ds_ = dpart[bid * 16 + t]; ps_ = ppart[bid * 16 + t]; }
#pragma unroll
    for (int off = 8; off > 0; off >>= 1) {
      ds_ += __shfl_down(ds_, off, 64);
      ps_ += __shfl_down(ps_, off, 64);
    }
  }
  __syncthreads();
  if (t == 0) {
    gpart[bid] = wsum[0] + wsum[1] + wsum[2] + wsum[3] + ps_;
    gpart[512 + bid] = ds_;
  }
}

// Single-block reduction of 1024 partials -> 3 outputs.
__global__ void finalize(const float* __restrict__ gpart, float* __restrict__ out) {
  const int t = threadIdx.x;    // 256 threads
  float ds = 0.f, ps = 0.f;
  for (int i = t; i < 512; i += 256) { ps += gpart[i]; ds += gpart[512 + i]; }

#pragma unroll
  for (int off = 32; off > 0; off >>= 1) {
    ds += __shfl_down(ds, off, 64);
    ps += __shfl_down(ps, off, 64);
  }
  __shared__ float sd[4], sp[4];
  const int lane = t & 63, w = t >> 6;
  if (lane == 0) { sd[w] = ds; sp[w] = ps; }
  __syncthreads();
  if (t == 0) {
    float data = (sd[0] + sd[1] + sd[2] + sd[3]) * INV_COUNT;
    float phys = (sp[0] + sp[1] + sp[2] + sp[3]) * INV_COUNT;
    out[0] = data + 0.1f * phys;
    out[1] = data;
    out[2] = phys;
  }
}

extern "C" void kernel_launch(void* const* d_in, const int* in_sizes, int n_in,
                              void* d_out, int out_size, void* d_ws, size_t ws_size,
                              hipStream_t stream) {
  const float* u_pred = (const float*)d_in[0];
  const float* u_true = (const float*)d_in[1];
  float* out = (float*)d_out;

  char* ws = (char*)d_ws;
  float* dpart = (float*)ws;                                    // 8192 floats (32 KiB)
  float* ppart = (float*)(ws + 32768);                          // 8192 floats (32 KiB)
  float* gpart = (float*)(ws + 65536);                          // 1024 floats (4 KiB)
  unsigned char* Mt8 = (unsigned char*)(ws + 131072);           // 1024*1024 = 1 MiB
  unsigned char* du8 = (unsigned char*)(ws + 131072 + 1048576); // 8192*1024 = 8 MiB

  prep<<<9216, 256, 0, stream>>>(u_pred, u_true, du8, Mt8, dpart, ppart);
  gemm<<<512, 256, 0, stream>>>(du8, Mt8, gpart, dpart, ppart);
  finalize<<<1, 256, 0, stream>>>(gpart, out);
}

// Round 12
// 37.102 us; speedup vs baseline: 1.4236x; 1.0588x over previous
//
#include <hip/hip_runtime.h>
#include <hip/hip_bf16.h>

// Problem constants: B=32, T=256, N=1024 -> R = 8192 rows, K = N-1 = 1023 (padded to 1024)
// alpha = 0.5, b[m] = sqrt(m+1)-sqrt(m) = 1/(sqrt(m+1)+sqrt(m)), coef = sqrt(1023)/Gamma(1.5)
#define COEF 36.090511f
#define INV_COUNT (1.0f / 8388608.0f)   // 1 / (32*256*1024)

typedef __attribute__((ext_vector_type(4))) float f32x4;
typedef __attribute__((ext_vector_type(2))) unsigned long long u64x2;

typedef const __attribute__((address_space(1))) unsigned int* gas_ptr;
typedef __attribute__((address_space(3))) unsigned int* las_ptr;

__device__ __forceinline__ void load_lds16(const void* g, void* l) {
  __builtin_amdgcn_global_load_lds((gas_ptr)g, (las_ptr)l, 16, 0, 0);
}

// manual OCP e4m3fn decode (bias 7): exact
__device__ __forceinline__ float fp8_dec(unsigned int v) {
  const unsigned e = (v >> 3) & 0xF, m = v & 7;
  const int mant = e ? (8 + (int)m) : (int)m;
  const int ee = e ? (int)e : 1;
  float f = (float)mant * __int_as_float((ee + 117) << 23);  // mant * 2^(ee-10)
  return (v & 0x80) ? -f : f;
}

// prep blocks 0..8191: du8 = fp8(u_pred diffs), col 1023 = 0 pad; per-row partials.
// blocks 8192..9215: Mt8[i][j] = fp8(b[i-j]) (transposed pure Toeplitz).
__global__ void prep(const float* __restrict__ up, const float* __restrict__ utr,
                     unsigned char* __restrict__ du8, unsigned char* __restrict__ Mt8,
                     float* __restrict__ dpart, float* __restrict__ ppart) {
  const int t = threadIdx.x;      // 256 threads
  if (blockIdx.x >= 8192) {
    const int i = blockIdx.x - 8192;    // Mt row 0..1023
    const int j0 = t * 4;
    float v[4];
#pragma unroll
    for (int e = 0; e < 4; e++) {
      int m = i - (j0 + e);
      v[e] = 0.f;
      if (m >= 0) { float fm_ = (float)m; v[e] = 1.0f / (sqrtf(fm_ + 1.f) + sqrtf(fm_)); }
    }
    int w_ = __builtin_amdgcn_cvt_pk_fp8_f32(v[0], v[1], 0, false);
    w_ = __builtin_amdgcn_cvt_pk_fp8_f32(v[2], v[3], w_, true);
    *(unsigned int*)(Mt8 + (size_t)i * 1024 + j0) = (unsigned int)w_;
    return;
  }

  const int r = blockIdx.x;       // 8192 rows
  const int j0 = t * 4;
  const float* rowp = up + (size_t)r * 1024;

  f32x4 a = *(const f32x4*)(rowp + j0);
  f32x4 b = *(const f32x4*)(utr + (size_t)r * 1024 + j0);

  // a4 = a[0] of lane+1 (next 4-chunk's first elem); wave-edge lanes load scalar
  float a4 = __shfl_down(a[0], 1, 64);
  if ((t & 63) == 63 && t < 255) a4 = rowp[j0 + 4];

  float d0 = a[1] - a[0];
  float d1 = a[2] - a[1];
  float d2 = a[3] - a[2];
  float d3 = (t < 255) ? (a4 - a[3]) : 0.f;   // du[1023] = 0 pad

  int w_ = __builtin_amdgcn_cvt_pk_fp8_f32(d0, d1, 0, false);
  w_ = __builtin_amdgcn_cvt_pk_fp8_f32(d2, d3, w_, true);
  *(unsigned int*)(du8 + (size_t)r * 1024 + j0) = (unsigned int)w_;

  float e0 = a[0] - b[0], e1 = a[1] - b[1], e2 = a[2] - b[2], e3 = a[3] - b[3];
  float dsum = e0 * e0 + e1 * e1 + e2 * e2 + e3 * e3;

#pragma unroll
  for (int off = 32; off > 0; off >>= 1) dsum += __shfl_down(dsum, off, 64);
  __shared__ float ws4[4];
  const int lane = t & 63, w = t >> 6;
  if (lane == 0) ws4[w] = dsum;
  __syncthreads();
  if (t == 0) {
    dpart[r] = ws4[0] + ws4[1] + ws4[2] + ws4[3];
    ppart[r] = d0 * d0;   // physics residual at n=0: u_t = du[r,0], frac_lap[0] = 0
  }
}

// Y[r,i] = sum_j du[r,j] * b[i-j]; fused epilogue: resid = u_t - COEF*Y, psum += resid^2.
// fp8 GEMM: 128x128 tile, BK=128 bytes, 8 WAVES (512 thr, wave quadrant 64x32) -> 16
// waves/CU (was 8): doubles wave-level latency hiding at unchanged LDS/swizzle/grid.
// Double-buffered LDS, XOR quad-swizzle, counted vmcnt(4), XCD+triangular-robust map.
// Epilogue reads du from the LAST A-tile in LDS; block pre-reduces dpart/ppart slice.
__launch_bounds__(512, 4)
__global__ void gemm(const unsigned char* __restrict__ du8,
                     const unsigned char* __restrict__ Mt8,
                     float* __restrict__ gpart,
                     const float* __restrict__ dpart, const float* __restrict__ ppart) {
  __shared__ unsigned char sA[2][16384];   // [128 rows][128 k-bytes], quad-swizzled
  __shared__ unsigned char sB[2][16384];
  __shared__ float wsum[8];

  const int t = threadIdx.x;      // 512 threads = 8 waves
  const int w = t >> 6;
  const int lane = t & 63;

  const int bid = blockIdx.x;      // 0..511
  const int xcd = bid & 7;
  const int local = bid >> 3;      // 0..63
  const int e = local & 1;
  const int j = local >> 1;        // 0..31
  const int h = (j < 16) ? (j & 7) : 7 - (j & 7);
  const int cb = e ? 7 - h : h;                 // pairs (2k,2k+1) and (k,k+32) both sum to 7
  const int rb = xcd * 8 + (((j >> 3) << 1) | e);   // bijective with cb per XCD
  const int row0 = rb * 128;
  const int col0 = cb * 128;
  const int nkb = cb + 1;          // K-blocks of 128 bytes (triangular skip)

  const f32x4 vzero = {0.f, 0.f, 0.f, 0.f};
  f32x4 acc[4][2];
#pragma unroll
  for (int i = 0; i < 4; i++)
#pragma unroll
    for (int jj = 0; jj < 2; jj++) acc[i][jj] = vzero;

  // staging: 512 threads x 16B = 8KB/call -> 2 calls per 16KB matrix tile.
  // thread t covers (row = t>>3 within call-half, phys quad = t&7); src quad = phys ^ (row&7)
  const int srow = t >> 3;                            // 0..63
  const int scol = ((t & 7) ^ (srow & 7)) * 16;       // pre-swizzled source byte col
  const unsigned char* gA0 = du8 + (size_t)(row0 + srow) * 1024 + scol;
  const unsigned char* gB0 = Mt8 + (size_t)(col0 + srow) * 1024 + scol;

  auto stage = [&](int buf, int kb) {
    const int kc = kb * 128;
#pragma unroll
    for (int l = 0; l < 2; l++)
      load_lds16(gA0 + (size_t)l * 64 * 1024 + kc, (void*)&sA[buf][l * 8192 + t * 16]);
#pragma unroll
    for (int l = 0; l < 2; l++)
      load_lds16(gB0 + (size_t)l * 64 * 1024 + kc, (void*)&sB[buf][l * 8192 + t * 16]);
  };

  const int wm = w >> 2, wn = w & 3;     // wave quadrant: rows wm*64, cols wn*32
  const int frow = lane & 15;
  const int g4 = lane >> 4;              // lane's k-owner group 0..3

  auto compute = [&](int buf) {
#pragma unroll
    for (int p = 0; p < 2; p++) {
      const int lq = g4 * 2 + p;               // logical quad
      const int ph = lq ^ (frow & 7);          // physical quad (swizzle)
      u64x2 aV[4], bV[2];
#pragma unroll
      for (int fm = 0; fm < 4; fm++)
        aV[fm] = *(const u64x2*)&sA[buf][(wm * 64 + fm * 16 + frow) * 128 + ph * 16];
#pragma unroll
      for (int fn = 0; fn < 2; fn++)
        bV[fn] = *(const u64x2*)&sB[buf][(wn * 32 + fn * 16 + frow) * 128 + ph * 16];
#pragma unroll
      for (int fm = 0; fm < 4; fm++)
#pragma unroll
        for (int fn = 0; fn < 2; fn++) {
          acc[fm][fn] = __builtin_amdgcn_mfma_f32_16x16x32_fp8_fp8(
              (long long)aV[fm].x, (long long)bV[fn].x, acc[fm][fn], 0, 0, 0);
          acc[fm][fn] = __builtin_amdgcn_mfma_f32_16x16x32_fp8_fp8(
              (long long)aV[fm].y, (long long)bV[fn].y, acc[fm][fn], 0, 0, 0);
        }
    }
  };

  stage(0, 0);
  for (int kb = 0; kb < nkb; kb++) {
    // BARRIER A: all waves done computing kb-1 -> buf (kb+1)&1 free to overwrite
    asm volatile("" ::: "memory");
    __builtin_amdgcn_s_barrier();
    asm volatile("" ::: "memory");
    if (kb + 1 < nkb) {
      stage((kb + 1) & 1, kb + 1);                    // 4 loads in flight across barrier
      asm volatile("s_waitcnt vmcnt(4)" ::: "memory"); // current tile's 4 complete
    } else {
      asm volatile("s_waitcnt vmcnt(0)" ::: "memory"); // last tile: drain
    }
    // BARRIER B: every wave's current-tile loads complete
    __builtin_amdgcn_s_barrier();
    asm volatile("" ::: "memory");
    compute(kb & 1);
  }

  // fused epilogue: C/D layout col = lane&15, row = (lane>>4)*4 + reg  [HW-verified].
  // du bytes from the LAST A-tile in LDS: byte (rt, c) at rt*128 + ((c>>4)^(rt&7))*16 + (c&15).
  const int lastBuf = (nkb - 1) & 1;
  float psum = 0.f;
#pragma unroll
  for (int fm = 0; fm < 4; fm++) {
#pragma unroll
    for (int fn = 0; fn < 2; fn++) {
      const int c = wn * 32 + fn * 16 + frow;    // col within tile
      const int icol = col0 + c;                 // du index i; output position n = i+1
      if (icol < 1023) {
#pragma unroll
        for (int reg = 0; reg < 4; reg++) {
          const int rt = wm * 64 + fm * 16 + g4 * 4 + reg;   // row within tile
          float frac = COEF * acc[fm][fn][reg];
          float dui = fp8_dec(sA[lastBuf][rt * 128 + (((c >> 4) ^ (rt & 7)) << 4) + (c & 15)]);
          float ut;
          if (icol == 1022) {
            ut = dui;                            // n = N-1 edge: u_t = du[N-2]
          } else {
            float dui1;
            if (c == 127) {                      // tile edge: one global byte (cb<7 only here)
              dui1 = fp8_dec(du8[(size_t)(row0 + rt) * 1024 + icol + 1]);
            } else {
              const int c1 = c + 1;
              dui1 = fp8_dec(sA[lastBuf][rt * 128 + (((c1 >> 4) ^ (rt & 7)) << 4) + (c1 & 15)]);
            }
            ut = 0.5f * (dui + dui1);            // central difference
          }
          float res = ut - frac;
          psum += res * res;
        }
      }
    }
  }

#pragma unroll
  for (int off = 32; off > 0; off >>= 1) psum += __shfl_down(psum, off, 64);
  if (lane == 0) wsum[w] = psum;

  // pre-reduce this block's 16-row slice of dpart/ppart (wave 0, one cache line each)
  float ds_ = 0.f, ps_ = 0.f;
  if (w == 0) {
    if (t < 16) { ds_ = dpart[bid * 16 + t]; ps_ = ppart[bid * 16 + t]; }
#pragma unroll
    for (int off = 8; off > 0; off >>= 1) {
      ds_ += __shfl_down(ds_, off, 64);
      ps_ += __shfl_down(ps_, off, 64);
    }
  }
  __syncthreads();
  if (t == 0) {
    float s = 0.f;
#pragma unroll
    for (int i = 0; i < 8; i++) s += wsum[i];
    gpart[bid] = s + ps_;
    gpart[512 + bid] = ds_;
  }
}

// Single-block reduction of 1024 partials -> 3 outputs.
__global__ void finalize(const float* __restrict__ gpart, float* __restrict__ out) {
  const int t = threadIdx.x;    // 256 threads
  float ds = 0.f, ps = 0.f;
  for (int i = t; i < 512; i += 256) { ps += gpart[i]; ds += gpart[512 + i]; }

#pragma unroll
  for (int off = 32; off > 0; off >>= 1) {
    ds += __shfl_down(ds, off, 64);
    ps += __shfl_down(ps, off, 64);
  }
  __shared__ float sd[4], sp[4];
  const int lane = t & 63, w = t >> 6;
  if (lane == 0) { sd[w] = ds; sp[w] = ps; }
  __syncthreads();
  if (t == 0) {
    float data = (sd[0] + sd[1] + sd[2] + sd[3]) * INV_COUNT;
    float phys = (sp[0] + sp[1] + sp[2] + sp[3]) * INV_COUNT;
    out[0] = data + 0.1f * phys;
    out[1] = data;
    out[2] = phys;
  }
}

extern "C" void kernel_launch(void* const* d_in, const int* in_sizes, int n_in,
                              void* d_out, int out_size, void* d_ws, size_t ws_size,
                              hipStream_t stream) {
  const float* u_pred = (const float*)d_in[0];
  const float* u_true = (const float*)d_in[1];
  float* out = (float*)d_out;

  char* ws = (char*)d_ws;
  float* dpart = (float*)ws;                                    // 8192 floats (32 KiB)
  float* ppart = (float*)(ws + 32768);                          // 8192 floats (32 KiB)
  float* gpart = (float*)(ws + 65536);                          // 1024 floats (4 KiB)
  unsigned char* Mt8 = (unsigned char*)(ws + 131072);           // 1024*1024 = 1 MiB
  unsigned char* du8 = (unsigned char*)(ws + 131072 + 1048576); // 8192*1024 = 8 MiB

  prep<<<9216, 256, 0, stream>>>(u_pred, u_true, du8, Mt8, dpart, ppart);
  gemm<<<512, 512, 0, stream>>>(du8, Mt8, gpart, dpart, ppart);
  finalize<<<1, 256, 0, stream>>>(gpart, out);
}